// Round 2
// baseline (1681.851 us; speedup 1.0000x reference)
//
#include <hip/hip_runtime.h>
#include <hip/hip_bf16.h>

typedef unsigned short u16;

#define DMODEL 1024
#define DI 2048
#define NST 16
#define RANK 64
#define BB 2
#define LL 2048
#define MM (BB*LL)
#define LC 64
#define NCH (LL/LC)

__device__ __forceinline__ float b2f(u16 v){
  union { unsigned int u; float f; } x; x.u = ((unsigned int)v)<<16; return x.f;
}
__device__ __forceinline__ u16 f2b(float f){
  union { unsigned int u; float f; } x; x.f = f;
  unsigned int r = x.u + 0x7FFFu + ((x.u>>16)&1u);   // RNE
  return (u16)(r>>16);
}
// flagged input load: bf==true -> buffer is bf16, else f32
__device__ __forceinline__ float ldf(const void* p, size_t i, bool bf){
  return bf ? b2f(((const u16*)p)[i]) : ((const float*)p)[i];
}
// dtype probe: A_log[1] = log(2). bf16 buffer: u16[1]=0x3F31 != 0.
// f32 buffer: u16[1] = high half of A_log[0]==0.0f -> 0.
__device__ __forceinline__ bool probe_bf(const u16* probe){ return probe[1] != 0; }

// Tiled GEMM: C[M,N] = A[M,K] (lda) * Bw[K,N] (input weight, row-major).
// AIN: 1 = A is a harness input (dtype-flagged), 0 = A is f32 workspace.
// EPI: 0 plain fp32->C0 (ldc=N); 1 split even/odd cols -> C0(x)/C1(z), ldc=DI;
//      2 softplus(acc+bias)->C0 (ldc=N); 3 flagged store ->Obf (ldc=N)
template<int AIN, int EPI>
__global__ __launch_bounds__(256) void gemm_k(
    const void* __restrict__ Av, const void* __restrict__ Bv,
    float* __restrict__ C0, float* __restrict__ C1,
    const void* __restrict__ biasv, void* __restrict__ Obf,
    const u16* __restrict__ probe,
    int M, int N, int K, int lda)
{
  const bool bf = probe_bf(probe);
  __shared__ float As[16][128];   // [k][m] transposed
  __shared__ float Bs[16][128];   // [k][n]
  const int tx = threadIdx.x;
  const int m0 = blockIdx.y*128, n0 = blockIdx.x*128;
  const int arow = tx>>1, acol = (tx&1)*8;
  const int brow = tx>>4, bcol = (tx&15)*8;
  const int tr = tx>>4, tc = tx&15;
  float acc[8][8];
#pragma unroll
  for(int i=0;i<8;i++)
#pragma unroll
    for(int j=0;j<8;j++) acc[i][j]=0.f;

  for(int k0=0;k0<K;k0+=16){     // K is always a multiple of 16 here
    float av[8], bv[8];
    const size_t abase = (size_t)(m0+arow)*lda + (k0+acol);
#pragma unroll
    for(int j=0;j<8;j++)
      av[j] = AIN ? ldf(Av, abase+j, bf) : ((const float*)Av)[abase+j];
    const size_t bbase = (size_t)(k0+brow)*N + (n0+bcol);
#pragma unroll
    for(int j=0;j<8;j++)
      bv[j] = (n0+bcol+j < N) ? ldf(Bv, bbase+j, bf) : 0.f;
    __syncthreads();
#pragma unroll
    for(int j=0;j<8;j++) As[acol+j][arow] = av[j];
#pragma unroll
    for(int j=0;j<8;j++) Bs[brow][bcol+j] = bv[j];
    __syncthreads();
#pragma unroll
    for(int kk=0;kk<16;kk++){
      float a[8], b[8];
#pragma unroll
      for(int i=0;i<8;i++) a[i]=As[kk][tr*8+i];
#pragma unroll
      for(int j=0;j<8;j++) b[j]=Bs[kk][tc*8+j];
#pragma unroll
      for(int i=0;i<8;i++)
#pragma unroll
        for(int j=0;j<8;j++) acc[i][j] = fmaf(a[i],b[j],acc[i][j]);
    }
  }
#pragma unroll
  for(int i=0;i<8;i++){
    int m = m0 + tr*8 + i;
#pragma unroll
    for(int j=0;j<8;j++){
      int n = n0 + tc*8 + j;
      if(n >= N) continue;
      float v = acc[i][j];
      if(EPI==0){
        C0[(size_t)m*N + n] = v;
      } else if(EPI==1){
        if(n & 1) C1[(size_t)m*DI + (n>>1)] = v;
        else      C0[(size_t)m*DI + (n>>1)] = v;
      } else if(EPI==2){
        v += ldf(biasv, n, bf);
        float sp = (v > 20.f) ? v : log1pf(__expf(v));
        C0[(size_t)m*N + n] = sp;
      } else {
        if(bf) ((u16*)Obf)[(size_t)m*N + n] = f2b(v);
        else   ((float*)Obf)[(size_t)m*N + n] = v;
      }
    }
  }
}

// Depthwise conv (K=4, SAME: pad_lo=1, pad_hi=2) + bias + silu
__global__ __launch_bounds__(256) void conv_silu_k(
  const float* __restrict__ x, const void* __restrict__ w,
  const void* __restrict__ bias, float* __restrict__ xc,
  const u16* __restrict__ probe)
{
  const bool bf = probe_bf(probe);
  int idx = blockIdx.x*256 + threadIdx.x;
  int d = idx & (DI-1);
  int t = (idx / DI) & (LL-1);
  int b = idx / (DI*LL);
  float acc = ldf(bias, d, bf);
#pragma unroll
  for(int k=0;k<4;k++){
    int tt = t - 1 + k;
    if(0<=tt && tt<LL) acc = fmaf(x[((size_t)b*LL+tt)*DI + d], ldf(w, k*DI + d, bf), acc);
  }
  xc[idx] = acc / (1.f + __expf(-acc));   // silu
}

// Phase A: per (chunk c, batch b, channel d) compute chunk affine map:
// ar[n] = prod dA, s[n] = chunk scan from state 0.  Layout out: [c][b][n][d]
__global__ __launch_bounds__(256) void scan_a_k(
  const float* __restrict__ delta, const float* __restrict__ xc,
  const float* __restrict__ xdbl, const u16* __restrict__ A_log,
  float* __restrict__ Aprod, float* __restrict__ Bacc)
{
  const bool bf = probe_bf(A_log);
  __shared__ float Bsh[LC][NST];
  const int d = blockIdx.x*256 + threadIdx.x;
  const int b = blockIdx.y, c = blockIdx.z;
  for(int i=threadIdx.x;i<LC*NST;i+=256){
    int l = i>>4, n = i&15;
    Bsh[l][n] = xdbl[((size_t)b*LL + (size_t)c*LC + l)*96 + 64 + n];
  }
  __syncthreads();
  float acoef[NST], ar[NST], s[NST];
#pragma unroll
  for(int n=0;n<NST;n++){
    acoef[n] = -__expf(ldf(A_log, (size_t)d*NST+n, bf));
    ar[n]=1.f; s[n]=0.f;
  }
  const size_t base0 = ((size_t)b*LL + (size_t)c*LC)*DI + d;
  for(int l=0;l<LC;l++){
    float dv = delta[base0 + (size_t)l*DI];
    float xv = xc[base0 + (size_t)l*DI];
    float du = dv*xv;
#pragma unroll
    for(int n=0;n<NST;n++){
      float dA = __expf(dv*acoef[n]);
      s[n] = fmaf(dA, s[n], du*Bsh[l][n]);
      ar[n] *= dA;
    }
  }
  const size_t ob = ((size_t)c*BB + b)*((size_t)NST*DI) + d;
#pragma unroll
  for(int n=0;n<NST;n++){
    Aprod[ob + (size_t)n*DI] = ar[n];
    Bacc [ob + (size_t)n*DI] = s[n];
  }
}

// Phase B: sequential prefix over chunks per scalar channel (b,n,d); stores
// the incoming state of each chunk. NOTE: Sin intentionally aliases Aprod
// (read-before-write at each address) -> NO __restrict__ here.
__global__ __launch_bounds__(256) void scan_b_k(
  const float* Aprod, const float* Bacc, float* Sin)
{
  const int idx = blockIdx.x*256 + threadIdx.x;   // over BB*NST*DI = 65536
  float s = 0.f;
  for(int c=0;c<NCH;c++){
    size_t off = (size_t)c*((size_t)BB*NST*DI) + idx;
    float a = Aprod[off];
    float bb = Bacc[off];
    Sin[off] = s;
    s = fmaf(a, s, bb);
  }
}

// Phase C: replay chunks from correct initial state, emit y.
// NOTE: y intentionally aliases delta (read-before-write per address) ->
// NO __restrict__ on delta/y.
__global__ __launch_bounds__(256) void scan_c_k(
  const float* delta, const float* __restrict__ xc,
  const float* __restrict__ xdbl, const u16* __restrict__ A_log,
  const float* __restrict__ Sin, float* y)
{
  const bool bf = probe_bf(A_log);
  __shared__ float Bsh[LC][NST], Csh[LC][NST];
  const int d = blockIdx.x*256 + threadIdx.x;
  const int b = blockIdx.y, c = blockIdx.z;
  for(int i=threadIdx.x;i<LC*NST;i+=256){
    int l = i>>4, n = i&15;
    size_t ro = ((size_t)b*LL + (size_t)c*LC + l)*96;
    Bsh[l][n] = xdbl[ro + 64 + n];
    Csh[l][n] = xdbl[ro + 80 + n];
  }
  __syncthreads();
  float acoef[NST], s[NST];
  const size_t ib = ((size_t)c*BB + b)*((size_t)NST*DI) + d;
#pragma unroll
  for(int n=0;n<NST;n++){
    acoef[n] = -__expf(ldf(A_log, (size_t)d*NST+n, bf));
    s[n] = Sin[ib + (size_t)n*DI];
  }
  const size_t base0 = ((size_t)b*LL + (size_t)c*LC)*DI + d;
  for(int l=0;l<LC;l++){
    float dv = delta[base0 + (size_t)l*DI];
    float xv = xc[base0 + (size_t)l*DI];
    float du = dv*xv;
    float yv = 0.f;
#pragma unroll
    for(int n=0;n<NST;n++){
      float dA = __expf(dv*acoef[n]);
      s[n] = fmaf(dA, s[n], du*Bsh[l][n]);
      yv = fmaf(s[n], Csh[l][n], yv);
    }
    y[base0 + (size_t)l*DI] = yv;
  }
}

// G = (y + xc*D) * silu(z)
__global__ __launch_bounds__(256) void gate_k(
  const float* __restrict__ y, const float* __restrict__ xc,
  const float* __restrict__ z, const void* __restrict__ Dw,
  float* __restrict__ G, const u16* __restrict__ probe)
{
  const bool bf = probe_bf(probe);
  int idx = blockIdx.x*256 + threadIdx.x;
  int d = idx & (DI-1);
  float zv = z[idx];
  float g = zv / (1.f + __expf(-zv));
  G[idx] = (y[idx] + xc[idx]*ldf(Dw, d, bf)) * g;
}

extern "C" void kernel_launch(void* const* d_in, const int* in_sizes, int n_in,
                              void* d_out, int out_size, void* d_ws, size_t ws_size,
                              hipStream_t stream)
{
  const void* hidden = d_in[0];
  const void* W_in   = d_in[1];
  const void* convw  = d_in[2];
  const void* convb  = d_in[3];
  const void* W_x    = d_in[4];
  const void* W_dt   = d_in[5];
  const void* b_dt   = d_in[6];
  const u16*  A_log  = (const u16*)d_in[7];   // also the dtype probe
  const void* Dw     = d_in[8];
  const void* W_out  = d_in[9];

  char* p = (char*)d_ws;
  float* x    = (float*)p; p += (size_t)MM*DI*4;     // 33.5 MB
  float* z    = (float*)p; p += (size_t)MM*DI*4;     // 33.5 MB
  float* xc   = (float*)p; p += (size_t)MM*DI*4;     // 33.5 MB
  float* dl   = (float*)p; p += (size_t)MM*DI*4;     // 33.5 MB (delta; y aliases it)
  float* xdbl = (float*)p; p += (size_t)MM*96*4;     // 1.6 MB
  float* Apd  = (float*)p; p += (size_t)NCH*BB*NST*DI*4;  // 8 MB (Sin aliases it)
  float* Bcc  = (float*)p; p += (size_t)NCH*BB*NST*DI*4;  // 8 MB
  float* yb  = dl;    // scan C reads delta[idx] then writes y[idx]: safe alias
  float* Sin = Apd;   // scan B reads Aprod[off] before writing Sin[off]: safe alias
  float* G   = x;     // x is dead after conv; gate writes G here

  // 1. xz = hidden @ W_in, split even/odd -> x, z
  gemm_k<1,1><<<dim3((2*DI)/128, MM/128), 256, 0, stream>>>(
      hidden, W_in, x, z, nullptr, nullptr, A_log, MM, 2*DI, DMODEL, DMODEL);
  // 2. xc = silu(depthwise_conv(x) + bias)
  conv_silu_k<<<(MM*DI)/256, 256, 0, stream>>>(x, convw, convb, xc, A_log);
  // 3. xdbl = xc @ W_x  (N=96)
  gemm_k<0,0><<<dim3(1, MM/128), 256, 0, stream>>>(
      xc, W_x, xdbl, nullptr, nullptr, nullptr, A_log, MM, 96, DI, DI);
  // 4. delta = softplus(xdbl[:, :64] @ W_dt + b_dt)
  gemm_k<0,2><<<dim3(DI/128, MM/128), 256, 0, stream>>>(
      xdbl, W_dt, dl, nullptr, b_dt, nullptr, A_log, MM, DI, RANK, 96);
  // 5. chunked selective scan
  scan_a_k<<<dim3(DI/256, BB, NCH), 256, 0, stream>>>(dl, xc, xdbl, A_log, Apd, Bcc);
  scan_b_k<<<(BB*NST*DI)/256, 256, 0, stream>>>(Apd, Bcc, Sin);
  scan_c_k<<<dim3(DI/256, BB, NCH), 256, 0, stream>>>(dl, xc, xdbl, A_log, Sin, yb);
  // 6. G = (y + xc*D) * silu(z)
  gate_k<<<(MM*DI)/256, 256, 0, stream>>>(yb, xc, z, Dw, G, A_log);
  // 7. out = G @ W_out (flagged store)
  gemm_k<0,3><<<dim3(DMODEL/128, MM/128), 256, 0, stream>>>(
      G, W_out, nullptr, nullptr, nullptr, d_out, A_log, MM, DMODEL, DI, DI);
}

// Round 5
// 457.193 us; speedup vs baseline: 3.6786x; 3.6786x over previous
//
#include <hip/hip_runtime.h>
#include <hip/hip_bf16.h>

typedef unsigned short u16;
typedef __attribute__((ext_vector_type(8))) short short8;
typedef __attribute__((ext_vector_type(4))) float f32x4;

#define DMODEL 1024
#define DI 2048
#define NST 16
#define RANK 64
#define BB 2
#define LL 2048
#define MM (BB*LL)
#define LC 64
#define NCH (LL/LC)

__device__ __forceinline__ float b2f(u16 v){ union{unsigned u; float f;}x; x.u=(unsigned)v<<16; return x.f; }
__device__ __forceinline__ u16 f2b(float f){
  union{unsigned u; float f;}x; x.f=f;
  unsigned r = x.u + 0x7FFFu + ((x.u>>16)&1u);   // RNE
  return (u16)(r>>16);
}
// dtype probe on A_log: A_log[0]=log(1)=0.0f. f32 buffer -> u16[1]=0x0000;
// bf16 buffer -> u16[1]=bf16(log 2)=0x3F31 != 0.  (Mechanism validated in R2.)
__device__ __forceinline__ bool probe_bf(const u16* probe){ return probe[1] != 0; }
// flagged scalar input load
__device__ __forceinline__ float ldin(const void* p, size_t i, bool bf){
  return bf ? b2f(((const u16*)p)[i]) : ((const float*)p)[i];
}
// flagged input -> bf16 bits
__device__ __forceinline__ u16 ldb(const void* p, size_t i, bool bf){
  return bf ? ((const u16*)p)[i] : f2b(((const float*)p)[i]);
}
// flagged 8-element input load -> bf16x8
__device__ __forceinline__ short8 ldin8(const void* p, size_t elem, bool bf){
  if(bf) return *(const short8*)((const u16*)p + elem);
  const float* f = (const float*)p + elem;
  short8 r;
#pragma unroll
  for(int j=0;j<8;j++) r[j] = (short)f2b(f[j]);
  return r;
}

// ---------------- MFMA GEMM: C[M,N] = A[M,K] * Bt[N,K]^T ----------------
// 128x128 tile, 4 waves (64x64 each = 4x4 of 16x16x32 bf16 MFMA), BK=32.
// LDS linear [128 rows][32 k] bf16 per operand (8KB each); chunk c = 4*row+q.
// Register staging (m93 pattern). Bt always internal bf16 workspace.
// AIN: 1 = A is a harness input (probe-flagged f32/bf16), 0 = A is bf16 ws.
// EPI: 0 = split even/odd cols -> x (f32, ld DI) / z (bf16 ws, ld DI)
//      1 = plain f32 store, ld = ldc
//      2 = flagged store to harness output (f32 or bf16 per probe), ld = ldc
template<int AIN, int EPI>
__global__ __launch_bounds__(256,2) void mgemm_k(
    const void* __restrict__ A, const u16* __restrict__ Bt,
    void* __restrict__ O0, void* __restrict__ O1,
    const u16* __restrict__ probe,
    int M, int N, int K, int ldc)
{
  const bool bf = probe_bf(probe);
  __shared__ char smem[16384];           // As 8KB | Bs 8KB
  const int t = threadIdx.x;
  const int m0 = blockIdx.y*128, n0 = blockIdx.x*128;
  const int lane = t & 63;
  const int wv = t >> 6;
  const int wm = (wv>>1)*64, wn = (wv&1)*64;
  const int lr = lane & 15, q = lane >> 4;

  // staging: thread t covers chunk t (rows 0-63) and t+256 (rows 64-127)
  const int r0 = t>>2, q0 = t&3;
  const size_t ae0 = (size_t)(m0 + r0)*K + q0*8;
  const size_t ae1 = (size_t)(m0 + 64 + r0)*K + q0*8;
  const u16* Bg0 = Bt + (size_t)(n0 + r0)*K + q0*8;
  const u16* Bg1 = Bt + (size_t)(n0 + 64 + r0)*K + q0*8;
  short8* lA0 = (short8*)(smem + t*16);
  short8* lA1 = (short8*)(smem + (t+256)*16);
  short8* lB0 = (short8*)(smem + 8192 + t*16);
  short8* lB1 = (short8*)(smem + 8192 + (t+256)*16);

  // fragment read offsets (bytes): row-major linear
  int aro[4], bro[4];
#pragma unroll
  for(int i=0;i<4;i++) aro[i] = (wm + i*16 + lr)*64 + q*16;
#pragma unroll
  for(int j=0;j<4;j++) bro[j] = (wn + j*16 + lr)*64 + q*16;

  f32x4 acc[4][4];
#pragma unroll
  for(int i=0;i<4;i++)
#pragma unroll
    for(int j=0;j<4;j++) acc[i][j] = (f32x4){0.f,0.f,0.f,0.f};

  for(int k0=0;k0<K;k0+=32){
    short8 va0, va1;
    if(AIN){ va0 = ldin8(A, ae0+k0, bf); va1 = ldin8(A, ae1+k0, bf); }
    else   { va0 = *(const short8*)((const u16*)A + ae0+k0);
             va1 = *(const short8*)((const u16*)A + ae1+k0); }
    short8 vb0 = *(const short8*)(Bg0 + k0);
    short8 vb1 = *(const short8*)(Bg1 + k0);
    __syncthreads();                 // all waves done reading prev tile
    *lA0 = va0; *lA1 = va1; *lB0 = vb0; *lB1 = vb1;
    __syncthreads();                 // tile fully staged
    short8 af[4], bfv[4];
#pragma unroll
    for(int i=0;i<4;i++) af[i] = *(const short8*)(smem + aro[i]);
#pragma unroll
    for(int j=0;j<4;j++) bfv[j] = *(const short8*)(smem + 8192 + bro[j]);
#pragma unroll
    for(int i=0;i<4;i++)
#pragma unroll
      for(int j=0;j<4;j++)
        acc[i][j] = __builtin_amdgcn_mfma_f32_16x16x32_bf16(af[i], bfv[j], acc[i][j], 0,0,0);
  }

  // C/D layout (m89-verified): col = lane&15, row = (lane>>4)*4 + reg
#pragma unroll
  for(int i=0;i<4;i++){
#pragma unroll
    for(int r=0;r<4;r++){
      int row = m0 + wm + i*16 + q*4 + r;
#pragma unroll
      for(int j=0;j<4;j++){
        int col = n0 + wn + j*16 + lr;
        float v = acc[i][j][r];
        if(EPI==0){
          if(col & 1) ((u16*)O1)[(size_t)row*DI + (col>>1)] = f2b(v);
          else        ((float*)O0)[(size_t)row*DI + (col>>1)] = v;
        } else if(EPI==1){
          ((float*)O0)[(size_t)row*ldc + col] = v;
        } else {
          if(bf) ((u16*)O0)[(size_t)row*ldc + col] = f2b(v);
          else   ((float*)O0)[(size_t)row*ldc + col] = v;
        }
      }
    }
  }
}

// ---------------- input transpose -> bf16, zero-pad dst rows C..Cp ----------------
// src[R][C] (probe-flagged dtype) -> dst[Cp][R] bf16
__global__ __launch_bounds__(256) void transpose_k(
    const void* __restrict__ src, u16* __restrict__ dst, int R, int C, int Cp,
    const u16* __restrict__ probe)
{
  const bool bf = probe_bf(probe);
  __shared__ u16 tile[32][33];
  const int c0 = blockIdx.x*32, r0 = blockIdx.y*32;
  const int tc = threadIdx.x & 31, tr0 = threadIdx.x >> 5;
#pragma unroll
  for(int i=0;i<4;i++){
    int r = tr0 + i*8;
    int gc = c0 + tc;
    tile[r][tc] = (gc < C) ? ldb(src, (size_t)(r0+r)*C + gc, bf) : (u16)0;
  }
  __syncthreads();
#pragma unroll
  for(int i=0;i<4;i++){
    int dr = c0 + tr0 + i*8;   // dst row = src col
    int dc = r0 + tc;          // dst col = src row
    dst[(size_t)dr*R + dc] = tile[tc][tr0 + i*8];
  }
}

// ---------------- VALU GEMM (K=64): dl = softplus(xdbl[:, :64] @ W_dt + b_dt)
__global__ __launch_bounds__(256) void vgemm_dt_k(
    const float* __restrict__ A, const void* __restrict__ Bw,
    const void* __restrict__ bias, float* __restrict__ C0,
    const u16* __restrict__ probe,
    int M, int N, int K, int lda)
{
  const bool bf = probe_bf(probe);
  __shared__ float As[16][128];
  __shared__ float Bs[16][128];
  const int tx = threadIdx.x;
  const int m0 = blockIdx.y*128, n0 = blockIdx.x*128;
  const int arow = tx>>1, acol = (tx&1)*8;
  const int brow = tx>>4, bcol = (tx&15)*8;
  const int tr = tx>>4, tc = tx&15;
  float acc[8][8];
#pragma unroll
  for(int i=0;i<8;i++)
#pragma unroll
    for(int j=0;j<8;j++) acc[i][j]=0.f;
  for(int k0=0;k0<K;k0+=16){
    float av[8], bv[8];
    const size_t ab = (size_t)(m0+arow)*lda + (k0+acol);
#pragma unroll
    for(int j=0;j<8;j++) av[j] = A[ab+j];
    const size_t bb = (size_t)(k0+brow)*N + (n0+bcol);
#pragma unroll
    for(int j=0;j<8;j++) bv[j] = ldin(Bw, bb+j, bf);
    __syncthreads();
#pragma unroll
    for(int j=0;j<8;j++) As[acol+j][arow] = av[j];
#pragma unroll
    for(int j=0;j<8;j++) Bs[brow][bcol+j] = bv[j];
    __syncthreads();
#pragma unroll
    for(int kk=0;kk<16;kk++){
      float a[8], b[8];
#pragma unroll
      for(int i=0;i<8;i++) a[i]=As[kk][tr*8+i];
#pragma unroll
      for(int j=0;j<8;j++) b[j]=Bs[kk][tc*8+j];
#pragma unroll
      for(int i=0;i<8;i++)
#pragma unroll
        for(int j=0;j<8;j++) acc[i][j] = fmaf(a[i],b[j],acc[i][j]);
    }
  }
#pragma unroll
  for(int i=0;i<8;i++){
    int m = m0 + tr*8 + i;
#pragma unroll
    for(int j=0;j<8;j++){
      int n = n0 + tc*8 + j;
      float v = acc[i][j] + ldin(bias, n, bf);
      C0[(size_t)m*N + n] = (v > 20.f) ? v : log1pf(__expf(v));
    }
  }
}

// ---------------- depthwise conv (K=4, pad 1 left / 2 right) + bias + silu ----------------
__global__ __launch_bounds__(256) void conv_silu_k(
  const float* __restrict__ x, const void* __restrict__ w,
  const void* __restrict__ bias, float* __restrict__ xc, u16* __restrict__ xcb,
  const u16* __restrict__ probe)
{
  const bool bf = probe_bf(probe);
  int idx = blockIdx.x*256 + threadIdx.x;
  int d = idx & (DI-1);
  int t = (idx / DI) & (LL-1);
  int b = idx / (DI*LL);
  float acc = ldin(bias, d, bf);
#pragma unroll
  for(int k=0;k<4;k++){
    int tt = t - 1 + k;
    if(0<=tt && tt<LL) acc = fmaf(x[((size_t)b*LL+tt)*DI + d], ldin(w, k*DI + d, bf), acc);
  }
  float s = acc / (1.f + __expf(-acc));
  xc[idx] = s;
  xcb[idx] = f2b(s);
}

// ---------------- chunked selective scan ----------------
__global__ __launch_bounds__(256) void scan_a_k(
  const float* __restrict__ delta, const float* __restrict__ xc,
  const float* __restrict__ xdbl, const void* __restrict__ A_log,
  float* __restrict__ Aprod, float* __restrict__ Bacc,
  const u16* __restrict__ probe)
{
  const bool bf = probe_bf(probe);
  __shared__ float Bsh[LC][NST];
  const int d = blockIdx.x*256 + threadIdx.x;
  const int b = blockIdx.y, c = blockIdx.z;
  for(int i=threadIdx.x;i<LC*NST;i+=256){
    int l = i>>4, n = i&15;
    Bsh[l][n] = xdbl[((size_t)b*LL + (size_t)c*LC + l)*128 + 64 + n];
  }
  __syncthreads();
  float acoef[NST], ar[NST], s[NST];
#pragma unroll
  for(int n=0;n<NST;n++){
    acoef[n] = -__expf(ldin(A_log, (size_t)d*NST+n, bf));
    ar[n]=1.f; s[n]=0.f;
  }
  const size_t base0 = ((size_t)b*LL + (size_t)c*LC)*DI + d;
  for(int l=0;l<LC;l++){
    float dv = delta[base0 + (size_t)l*DI];
    float xv = xc[base0 + (size_t)l*DI];
    float du = dv*xv;
#pragma unroll
    for(int n=0;n<NST;n++){
      float dA = __expf(dv*acoef[n]);
      s[n] = fmaf(dA, s[n], du*Bsh[l][n]);
      ar[n] *= dA;
    }
  }
  const size_t ob = ((size_t)c*BB + b)*((size_t)NST*DI) + d;
#pragma unroll
  for(int n=0;n<NST;n++){
    Aprod[ob + (size_t)n*DI] = ar[n];
    Bacc [ob + (size_t)n*DI] = s[n];
  }
}

// Phase B: prefix over chunks; Sin aliases Aprod (read-before-write) -> no __restrict__
__global__ __launch_bounds__(256) void scan_b_k(
  const float* Aprod, const float* Bacc, float* Sin)
{
  const int idx = blockIdx.x*256 + threadIdx.x;
  float s = 0.f;
  for(int c=0;c<NCH;c++){
    size_t off = (size_t)c*((size_t)BB*NST*DI) + idx;
    float a = Aprod[off];
    float bb = Bacc[off];
    Sin[off] = s;
    s = fmaf(a, s, bb);
  }
}

// Phase C: replay with true initial state; y aliases delta -> no __restrict__ on those
__global__ __launch_bounds__(256) void scan_c_k(
  const float* delta, const float* __restrict__ xc,
  const float* __restrict__ xdbl, const void* __restrict__ A_log,
  const float* __restrict__ Sin, float* y,
  const u16* __restrict__ probe)
{
  const bool bf = probe_bf(probe);
  __shared__ float Bsh[LC][NST], Csh[LC][NST];
  const int d = blockIdx.x*256 + threadIdx.x;
  const int b = blockIdx.y, c = blockIdx.z;
  for(int i=threadIdx.x;i<LC*NST;i+=256){
    int l = i>>4, n = i&15;
    size_t ro = ((size_t)b*LL + (size_t)c*LC + l)*128;
    Bsh[l][n] = xdbl[ro + 64 + n];
    Csh[l][n] = xdbl[ro + 80 + n];
  }
  __syncthreads();
  float acoef[NST], s[NST];
  const size_t ib = ((size_t)c*BB + b)*((size_t)NST*DI) + d;
#pragma unroll
  for(int n=0;n<NST;n++){
    acoef[n] = -__expf(ldin(A_log, (size_t)d*NST+n, bf));
    s[n] = Sin[ib + (size_t)n*DI];
  }
  const size_t base0 = ((size_t)b*LL + (size_t)c*LC)*DI + d;
  for(int l=0;l<LC;l++){
    float dv = delta[base0 + (size_t)l*DI];
    float xv = xc[base0 + (size_t)l*DI];
    float du = dv*xv;
    float yv = 0.f;
#pragma unroll
    for(int n=0;n<NST;n++){
      float dA = __expf(dv*acoef[n]);
      s[n] = fmaf(dA, s[n], du*Bsh[l][n]);
      yv = fmaf(s[n], Csh[l][n], yv);
    }
    y[base0 + (size_t)l*DI] = yv;
  }
}

// G = (y + xc*D) * silu(z)   (z bf16 ws in, G bf16 ws out)
__global__ __launch_bounds__(256) void gate_k(
  const float* __restrict__ y, const float* __restrict__ xc,
  const u16* __restrict__ zb, const void* __restrict__ Dw,
  u16* __restrict__ G, const u16* __restrict__ probe)
{
  const bool bf = probe_bf(probe);
  int idx = blockIdx.x*256 + threadIdx.x;
  int d = idx & (DI-1);
  float zv = b2f(zb[idx]);
  float g = zv / (1.f + __expf(-zv));
  G[idx] = f2b((y[idx] + xc[idx]*ldin(Dw, d, bf)) * g);
}

extern "C" void kernel_launch(void* const* d_in, const int* in_sizes, int n_in,
                              void* d_out, int out_size, void* d_ws, size_t ws_size,
                              hipStream_t stream)
{
  const void* hidden = d_in[0];
  const void* W_in   = d_in[1];
  const void* convw  = d_in[2];
  const void* convb  = d_in[3];
  const void* W_x    = d_in[4];
  const void* W_dt   = d_in[5];
  const void* b_dt   = d_in[6];
  const u16*  A_log  = (const u16*)d_in[7];   // also the dtype probe
  const void* Dw     = d_in[8];
  const void* W_out  = d_in[9];

  char* p = (char*)d_ws;
  float* x    = (float*)p;                       // 33.5 MB, dead after conv
  float* Apd  = (float*)p;                       //   alias: 8 MB
  float* Bcc  = (float*)(p + 8388608);           //   alias: 8 MB
  u16*   G    = (u16*)  (p + 16777216);          //   alias: 16.8 MB
  u16*   zb   = (u16*)  (p + 33554432);          // 16.8 MB
  float* xc   = (float*)(p + 50331648);          // 33.5 MB
  u16*   xcb  = (u16*)  (p + 83886080);          // 16.8 MB
  float* dl   = (float*)(p + 100663296);         // 33.5 MB (delta; y aliases)
  float* xdbl = (float*)(p + 134217728);         // 2.1 MB, [M][128] padded
  u16*   WinT = (u16*)  (p + 136314880);         // 8.4 MB  [4096][1024] bf16
  u16*   WoutT= (u16*)  (p + 144703488);         // 4.2 MB  [1024][2048] bf16
  u16*   WxT  = (u16*)  (p + 148897792);         // 0.5 MB  [128][2048] bf16, zero-padded
  float* yb   = dl;
  float* Sin  = Apd;

  // weight transposes -> bf16 (one-shot)
  transpose_k<<<dim3(128,32), 256, 0, stream>>>(W_in,  WinT,  DMODEL, 2*DI, 2*DI, A_log);
  transpose_k<<<dim3(32,64),  256, 0, stream>>>(W_out, WoutT, DI, DMODEL, DMODEL, A_log);
  transpose_k<<<dim3(4,64),   256, 0, stream>>>(W_x,   WxT,   DI, 96, 128, A_log);

  // 1. xz = hidden @ W_in -> x (f32) / z (bf16), even/odd split
  mgemm_k<1,0><<<dim3(32,32), 256, 0, stream>>>(hidden, WinT, x, zb, A_log, MM, 2*DI, DMODEL, 0);
  // 2. xc = silu(conv(x)+bias)  (f32 + bf16 copies)
  conv_silu_k<<<(MM*DI)/256, 256, 0, stream>>>(x, convw, convb, xc, xcb, A_log);
  // 3. xdbl = xc @ W_x  (N padded to 128)
  mgemm_k<0,1><<<dim3(1,32), 256, 0, stream>>>(xcb, WxT, xdbl, nullptr, A_log, MM, 128, DI, 128);
  // 4. delta = softplus(xdbl[:, :64] @ W_dt + b_dt)
  vgemm_dt_k<<<dim3(DI/128, MM/128), 256, 0, stream>>>(xdbl, W_dt, b_dt, dl, A_log, MM, DI, RANK, 128);
  // 5. chunked selective scan
  scan_a_k<<<dim3(DI/256, BB, NCH), 256, 0, stream>>>(dl, xc, xdbl, A_log, Apd, Bcc, A_log);
  scan_b_k<<<(BB*NST*DI)/256, 256, 0, stream>>>(Apd, Bcc, Sin);
  scan_c_k<<<dim3(DI/256, BB, NCH), 256, 0, stream>>>(dl, xc, xdbl, A_log, Sin, yb, A_log);
  // 6. G = (y + xc*D) * silu(z)  (bf16)
  gate_k<<<(MM*DI)/256, 256, 0, stream>>>(yb, xc, zb, Dw, G, A_log);
  // 7. out = G @ W_out (store dtype per probe)
  mgemm_k<0,2><<<dim3(DMODEL/128, MM/128), 256, 0, stream>>>(G, WoutT, d_out, nullptr, A_log, MM, DMODEL, DI, DMODEL);
}

// Round 6
// 405.150 us; speedup vs baseline: 4.1512x; 1.1285x over previous
//
#include <hip/hip_runtime.h>
#include <hip/hip_bf16.h>

typedef unsigned short u16;
typedef __attribute__((ext_vector_type(8))) short short8;
typedef __attribute__((ext_vector_type(4))) float f32x4;
typedef __attribute__((ext_vector_type(4))) float float4v;

#define DMODEL 1024
#define DI 2048
#define NST 16
#define RANK 64
#define BB 2
#define LL 2048
#define MM (BB*LL)
#define LC 64
#define NCH (LL/LC)

__device__ __forceinline__ float b2f(u16 v){ union{unsigned u; float f;}x; x.u=(unsigned)v<<16; return x.f; }
__device__ __forceinline__ u16 f2b(float f){
  union{unsigned u; float f;}x; x.f=f;
  unsigned r = x.u + 0x7FFFu + ((x.u>>16)&1u);   // RNE
  return (u16)(r>>16);
}
// dtype probe on A_log: A_log[0]=log(1)=0.0f. f32 buffer -> u16[1]==0 (R5-validated: f32).
__device__ __forceinline__ bool probe_bf(const u16* probe){ return probe[1] != 0; }
__device__ __forceinline__ float ldin(const void* p, size_t i, bool bf){
  return bf ? b2f(((const u16*)p)[i]) : ((const float*)p)[i];
}
__device__ __forceinline__ u16 ldb(const void* p, size_t i, bool bf){
  return bf ? ((const u16*)p)[i] : f2b(((const float*)p)[i]);
}
// async global->LDS, 16B/lane; lds base MUST be wave-uniform (HW scatters lane*16)
__device__ __forceinline__ void gl16(const u16* g, char* lds_wave_base){
  __builtin_amdgcn_global_load_lds((const __attribute__((address_space(1))) unsigned*)g,
                                   (__attribute__((address_space(3))) unsigned*)lds_wave_base, 16, 0, 0);
}

// ---------------- MFMA GEMM: C[M,N] = A[M,K] * Bt[N,K]^T  (all bf16 ws) ----------------
// 128x128 tile, 4 waves (64x64 = 4x4 of 16x16x32 MFMA), BK=32, global_load_lds
// width-16 staging (m97 structure), linear LDS [128 rows][32 k] per operand.
// blockIdx.z = K-split segment (K param = segment length).
// EPI: 0 split even/odd cols -> x f32 / zb bf16 (ld DI)
//      1 f32 partial store to O0 + z*M*ldc
//      2 flagged final store (f32/bf16 per probe)
//      3 softplus(v + bias[col]) -> f32 O0
template<int EPI>
__global__ __launch_bounds__(256,2) void mgemm_k(
    const u16* __restrict__ A, const u16* __restrict__ Bt,
    void* __restrict__ O0, void* __restrict__ O1,
    const void* __restrict__ bias, const u16* __restrict__ probe,
    int M, int N, int K, int lda, int ldb, int ldc)
{
  const bool bf = probe_bf(probe);
  __shared__ char smem[16384];           // As 8KB | Bs 8KB
  const int t = threadIdx.x;
  const int m0 = blockIdx.y*128, n0 = blockIdx.x*128;
  const int kbeg = blockIdx.z * K;
  const int lane = t & 63;
  const int wv = t >> 6;
  const int wm = (wv>>1)*64, wn = (wv&1)*64;
  const int lr = lane & 15, q = lane >> 4;

  // staging: thread t feeds LDS slot t (rows 0-63) and t+256 (rows 64-127)
  const int r0 = t>>2, q0 = t&3;
  const u16* Ag0 = A + kbeg + (size_t)(m0 + r0)*lda + q0*8;
  const u16* Ag1 = A + kbeg + (size_t)(m0 + 64 + r0)*lda + q0*8;
  const u16* Bg0 = Bt + kbeg + (size_t)(n0 + r0)*ldb + q0*8;
  const u16* Bg1 = Bt + kbeg + (size_t)(n0 + 64 + r0)*ldb + q0*8;
  char* const wbase = smem + (t & ~63)*16;   // wave-uniform
  char* const lA0 = wbase;
  char* const lA1 = wbase + 4096;
  char* const lB0 = wbase + 8192;
  char* const lB1 = wbase + 12288;

  // fragment read offsets (bytes): row-major linear
  int aro[4], bro[4];
#pragma unroll
  for(int i=0;i<4;i++) aro[i] = (wm + i*16 + lr)*64 + q*16;
#pragma unroll
  for(int j=0;j<4;j++) bro[j] = (wn + j*16 + lr)*64 + q*16;

  f32x4 acc[4][4];
#pragma unroll
  for(int i=0;i<4;i++)
#pragma unroll
    for(int j=0;j<4;j++) acc[i][j] = (f32x4){0.f,0.f,0.f,0.f};

  for(int k0=0;k0<K;k0+=32){
    __syncthreads();                 // all waves done reading prev tile
    gl16(Ag0 + k0, lA0); gl16(Ag1 + k0, lA1);
    gl16(Bg0 + k0, lB0); gl16(Bg1 + k0, lB1);
    __syncthreads();                 // drains vmcnt -> LDS visible
    short8 af[4], bfv[4];
#pragma unroll
    for(int i=0;i<4;i++) af[i] = *(const short8*)(smem + aro[i]);
#pragma unroll
    for(int j=0;j<4;j++) bfv[j] = *(const short8*)(smem + 8192 + bro[j]);
#pragma unroll
    for(int i=0;i<4;i++)
#pragma unroll
      for(int j=0;j<4;j++)
        acc[i][j] = __builtin_amdgcn_mfma_f32_16x16x32_bf16(af[i], bfv[j], acc[i][j], 0,0,0);
  }

  // C/D layout: col = lane&15, row = (lane>>4)*4 + reg
#pragma unroll
  for(int i=0;i<4;i++){
#pragma unroll
    for(int r=0;r<4;r++){
      int row = m0 + wm + i*16 + q*4 + r;
#pragma unroll
      for(int j=0;j<4;j++){
        int col = n0 + wn + j*16 + lr;
        float v = acc[i][j][r];
        if(EPI==0){
          if(col & 1) ((u16*)O1)[(size_t)row*DI + (col>>1)] = f2b(v);
          else        ((float*)O0)[(size_t)row*DI + (col>>1)] = v;
        } else if(EPI==1){
          ((float*)O0)[(size_t)blockIdx.z*M*ldc + (size_t)row*ldc + col] = v;
        } else if(EPI==2){
          if(bf) ((u16*)O0)[(size_t)row*ldc + col] = f2b(v);
          else   ((float*)O0)[(size_t)row*ldc + col] = v;
        } else {
          float s = v + ldin(bias, col, bf);
          ((float*)O0)[(size_t)row*ldc + col] = (s > 20.f) ? s : log1pf(__expf(s));
        }
      }
    }
  }
}

// ---------------- flagged convert: input (f32/bf16) -> bf16 ws, 8 elems/thread ----------------
__global__ __launch_bounds__(256) void cvt_k(
    const void* __restrict__ src, u16* __restrict__ dst, const u16* __restrict__ probe)
{
  const bool bf = probe_bf(probe);
  size_t i = ((size_t)blockIdx.x*256 + threadIdx.x)*8;
  if(bf){
    *(short8*)(dst+i) = *(const short8*)((const u16*)src + i);
  } else {
    float4v a = *(const float4v*)((const float*)src + i);
    float4v b = *(const float4v*)((const float*)src + i + 4);
    short8 r;
    r[0]=(short)f2b(a[0]); r[1]=(short)f2b(a[1]); r[2]=(short)f2b(a[2]); r[3]=(short)f2b(a[3]);
    r[4]=(short)f2b(b[0]); r[5]=(short)f2b(b[1]); r[6]=(short)f2b(b[2]); r[7]=(short)f2b(b[3]);
    *(short8*)(dst+i) = r;
  }
}

// ---------------- split-K reduce: xdbl = sum_z Pw[z], + bf16 copy ----------------
__global__ __launch_bounds__(256) void redx_k(
    const float* __restrict__ P, float* __restrict__ xdbl, u16* __restrict__ xdblb)
{
  size_t idx = (size_t)blockIdx.x*256 + threadIdx.x;   // over M*128
  float s = 0.f;
#pragma unroll
  for(int z=0;z<8;z++) s += P[(size_t)z*MM*128 + idx];
  xdbl[idx] = s;
  xdblb[idx] = f2b(s);
}

// ---------------- input transpose -> bf16, zero-pad dst rows C..Cp ----------------
// src[R][C] (flagged dtype) -> dst[Cp][R] bf16
__global__ __launch_bounds__(256) void transpose_k(
    const void* __restrict__ src, u16* __restrict__ dst, int R, int C, int Cp,
    const u16* __restrict__ probe)
{
  const bool bf = probe_bf(probe);
  __shared__ u16 tile[32][33];
  const int c0 = blockIdx.x*32, r0 = blockIdx.y*32;
  const int tc = threadIdx.x & 31, tr0 = threadIdx.x >> 5;
#pragma unroll
  for(int i=0;i<4;i++){
    int r = tr0 + i*8;
    int gc = c0 + tc;
    tile[r][tc] = (gc < C) ? ldb(src, (size_t)(r0+r)*C + gc, bf) : (u16)0;
  }
  __syncthreads();
#pragma unroll
  for(int i=0;i<4;i++){
    int dr = c0 + tr0 + i*8;   // dst row = src col
    int dc = r0 + tc;          // dst col = src row
    dst[(size_t)dr*R + dc] = tile[tc][tr0 + i*8];
  }
}

// ---------------- depthwise conv (K=4, pad 1 left / 2 right) + bias + silu ----------------
__global__ __launch_bounds__(256) void conv_silu_k(
  const float* __restrict__ x, const void* __restrict__ w,
  const void* __restrict__ bias, float* __restrict__ xc, u16* __restrict__ xcb,
  const u16* __restrict__ probe)
{
  const bool bf = probe_bf(probe);
  int idx = blockIdx.x*256 + threadIdx.x;
  int d = idx & (DI-1);
  int t = (idx / DI) & (LL-1);
  int b = idx / (DI*LL);
  float acc = ldin(bias, d, bf);
#pragma unroll
  for(int k=0;k<4;k++){
    int tt = t - 1 + k;
    if(0<=tt && tt<LL) acc = fmaf(x[((size_t)b*LL+tt)*DI + d], ldin(w, k*DI + d, bf), acc);
  }
  float s = acc / (1.f + __expf(-acc));
  xc[idx] = s;
  xcb[idx] = f2b(s);
}

// ---------------- chunked selective scan ----------------
__global__ __launch_bounds__(256) void scan_a_k(
  const float* __restrict__ delta, const float* __restrict__ xc,
  const float* __restrict__ xdbl, const void* __restrict__ A_log,
  float* __restrict__ Aprod, float* __restrict__ Bacc,
  const u16* __restrict__ probe)
{
  const bool bf = probe_bf(probe);
  __shared__ float Bsh[LC][NST];
  const int d = blockIdx.x*256 + threadIdx.x;
  const int b = blockIdx.y, c = blockIdx.z;
  for(int i=threadIdx.x;i<LC*NST;i+=256){
    int l = i>>4, n = i&15;
    Bsh[l][n] = xdbl[((size_t)b*LL + (size_t)c*LC + l)*128 + 64 + n];
  }
  __syncthreads();
  float acoef[NST], ar[NST], s[NST];
#pragma unroll
  for(int n=0;n<NST;n++){
    acoef[n] = -__expf(ldin(A_log, (size_t)d*NST+n, bf));
    ar[n]=1.f; s[n]=0.f;
  }
  const size_t base0 = ((size_t)b*LL + (size_t)c*LC)*DI + d;
  for(int l=0;l<LC;l++){
    float dv = delta[base0 + (size_t)l*DI];
    float xv = xc[base0 + (size_t)l*DI];
    float du = dv*xv;
#pragma unroll
    for(int n=0;n<NST;n++){
      float dA = __expf(dv*acoef[n]);
      s[n] = fmaf(dA, s[n], du*Bsh[l][n]);
      ar[n] *= dA;
    }
  }
  const size_t ob = ((size_t)c*BB + b)*((size_t)NST*DI) + d;
#pragma unroll
  for(int n=0;n<NST;n++){
    Aprod[ob + (size_t)n*DI] = ar[n];
    Bacc [ob + (size_t)n*DI] = s[n];
  }
}

// Phase B: prefix over chunks; Sin aliases Aprod (read-before-write) -> no __restrict__
__global__ __launch_bounds__(256) void scan_b_k(
  const float* Aprod, const float* Bacc, float* Sin)
{
  const int idx = blockIdx.x*256 + threadIdx.x;
  float s = 0.f;
  for(int c=0;c<NCH;c++){
    size_t off = (size_t)c*((size_t)BB*NST*DI) + idx;
    float a = Aprod[off];
    float bb = Bacc[off];
    Sin[off] = s;
    s = fmaf(a, s, bb);
  }
}

// Phase C: replay with true initial state; y aliases delta -> no __restrict__ on those
__global__ __launch_bounds__(256) void scan_c_k(
  const float* delta, const float* __restrict__ xc,
  const float* __restrict__ xdbl, const void* __restrict__ A_log,
  const float* __restrict__ Sin, float* y,
  const u16* __restrict__ probe)
{
  const bool bf = probe_bf(probe);
  __shared__ float Bsh[LC][NST], Csh[LC][NST];
  const int d = blockIdx.x*256 + threadIdx.x;
  const int b = blockIdx.y, c = blockIdx.z;
  for(int i=threadIdx.x;i<LC*NST;i+=256){
    int l = i>>4, n = i&15;
    size_t ro = ((size_t)b*LL + (size_t)c*LC + l)*128;
    Bsh[l][n] = xdbl[ro + 64 + n];
    Csh[l][n] = xdbl[ro + 80 + n];
  }
  __syncthreads();
  float acoef[NST], s[NST];
  const size_t ib = ((size_t)c*BB + b)*((size_t)NST*DI) + d;
#pragma unroll
  for(int n=0;n<NST;n++){
    acoef[n] = -__expf(ldin(A_log, (size_t)d*NST+n, bf));
    s[n] = Sin[ib + (size_t)n*DI];
  }
  const size_t base0 = ((size_t)b*LL + (size_t)c*LC)*DI + d;
  for(int l=0;l<LC;l++){
    float dv = delta[base0 + (size_t)l*DI];
    float xv = xc[base0 + (size_t)l*DI];
    float du = dv*xv;
    float yv = 0.f;
#pragma unroll
    for(int n=0;n<NST;n++){
      float dA = __expf(dv*acoef[n]);
      s[n] = fmaf(dA, s[n], du*Bsh[l][n]);
      yv = fmaf(s[n], Csh[l][n], yv);
    }
    y[base0 + (size_t)l*DI] = yv;
  }
}

// G = (y + xc*D) * silu(z)   (z bf16 ws in, G bf16 ws out)
__global__ __launch_bounds__(256) void gate_k(
  const float* __restrict__ y, const float* __restrict__ xc,
  const u16* __restrict__ zb, const void* __restrict__ Dw,
  u16* __restrict__ G, const u16* __restrict__ probe)
{
  const bool bf = probe_bf(probe);
  int idx = blockIdx.x*256 + threadIdx.x;
  int d = idx & (DI-1);
  float zv = b2f(zb[idx]);
  float g = zv / (1.f + __expf(-zv));
  G[idx] = f2b((y[idx] + xc[idx]*ldin(Dw, d, bf)) * g);
}

extern "C" void kernel_launch(void* const* d_in, const int* in_sizes, int n_in,
                              void* d_out, int out_size, void* d_ws, size_t ws_size,
                              hipStream_t stream)
{
  const void* hidden = d_in[0];
  const void* W_in   = d_in[1];
  const void* convw  = d_in[2];
  const void* convb  = d_in[3];
  const void* W_x    = d_in[4];
  const void* W_dt   = d_in[5];
  const void* b_dt   = d_in[6];
  const u16*  A_log  = (const u16*)d_in[7];   // also the dtype probe
  const void* Dw     = d_in[8];
  const void* W_out  = d_in[9];

  char* p = (char*)d_ws;
  float* x    = (float*)p;                       // 33.5 MB, dead after conv
  float* Apd  = (float*)p;                       //   alias: 8 MB
  float* Bcc  = (float*)(p + 8388608);           //   alias: 8 MB
  u16*   G    = (u16*)  (p + 16777216);          //   alias: 16.8 MB
  u16*   zb   = (u16*)  (p + 33554432);          // 16.8 MB
  float* xc   = (float*)(p + 50331648);          // 33.5 MB
  u16*   xcb  = (u16*)  (p + 83886080);          // 16.8 MB
  float* dl   = (float*)(p + 100663296);         // 33.5 MB region:
  float* Pw   = (float*)(p + 100663296);         //   alias: split-K partials 16.8 MB (dead before dl written)
  u16*   hb   = (u16*)  (p + 117440512);         //   alias: hidden bf16 8.4 MB (dead before dl written)
  float* xdbl = (float*)(p + 134217728);         // 2.1 MB  [M][128] f32
  u16*   xdblb= (u16*)  (p + 136314880);         // 1.05 MB [M][128] bf16
  u16*   WinT = (u16*)  (p + 137363456);         // 8.4 MB  [4096][1024]
  u16*   WoutT= (u16*)  (p + 145752064);         // 4.2 MB  [1024][2048]
  u16*   WxT  = (u16*)  (p + 149946368);         // 0.5 MB  [128][2048] zero-padded
  u16*   WdtT = (u16*)  (p + 150470656);         // 0.25 MB [2048][64]
  float* yb   = dl;
  float* Sin  = Apd;

  // one-shot weight transposes -> bf16, + hidden convert
  transpose_k<<<dim3(128,32), 256, 0, stream>>>(W_in,  WinT,  DMODEL, 2*DI, 2*DI, A_log);
  transpose_k<<<dim3(32,64),  256, 0, stream>>>(W_out, WoutT, DI, DMODEL, DMODEL, A_log);
  transpose_k<<<dim3(4,64),   256, 0, stream>>>(W_x,   WxT,   DI, 96, 128, A_log);
  transpose_k<<<dim3(64,2),   256, 0, stream>>>(W_dt,  WdtT,  RANK, DI, DI, A_log);
  cvt_k<<<(MM*DMODEL)/(256*8), 256, 0, stream>>>(hidden, hb, A_log);

  // 1. xz = hidden @ W_in -> x (f32) / z (bf16), even/odd split
  mgemm_k<0><<<dim3(32,32), 256, 0, stream>>>(hb, WinT, x, zb, nullptr, A_log,
                                              MM, 2*DI, DMODEL, DMODEL, DMODEL, 0);
  // 2. xc = silu(conv(x)+bias)
  conv_silu_k<<<(MM*DI)/256, 256, 0, stream>>>(x, convw, convb, xc, xcb, A_log);
  // 3. xdbl = xc @ W_x  (N padded to 128), split-K x8 -> partials -> reduce
  mgemm_k<1><<<dim3(1,32,8), 256, 0, stream>>>(xcb, WxT, Pw, nullptr, nullptr, A_log,
                                               MM, 128, DI/8, DI, DI, 128);
  redx_k<<<(MM*128)/256, 256, 0, stream>>>(Pw, xdbl, xdblb);
  // 4. delta = softplus(xdbl[:, :64] @ W_dt + b_dt)  (MFMA, K=64)
  mgemm_k<3><<<dim3(16,32), 256, 0, stream>>>(xdblb, WdtT, dl, nullptr, b_dt, A_log,
                                              MM, DI, RANK, 128, RANK, DI);
  // 5. chunked selective scan
  scan_a_k<<<dim3(DI/256, BB, NCH), 256, 0, stream>>>(dl, xc, xdbl, A_log, Apd, Bcc, A_log);
  scan_b_k<<<(BB*NST*DI)/256, 256, 0, stream>>>(Apd, Bcc, Sin);
  scan_c_k<<<dim3(DI/256, BB, NCH), 256, 0, stream>>>(dl, xc, xdbl, A_log, Sin, yb, A_log);
  // 6. G = (y + xc*D) * silu(z)
  gate_k<<<(MM*DI)/256, 256, 0, stream>>>(yb, xc, zb, Dw, G, A_log);
  // 7. out = G @ W_out (store dtype per probe)
  mgemm_k<2><<<dim3(DMODEL/128, MM/128), 256, 0, stream>>>(G, WoutT, d_out, nullptr, nullptr, A_log,
                                                           MM, DMODEL, DI, DI, DI, DMODEL);
}